// Round 7
// baseline (476.274 us; speedup 1.0000x reference)
//
#include <hip/hip_runtime.h>
#include <cstddef>
#include <cstdint>

#define N_NODES 170
#define SEQ 12
#define BATCH 32
#define DM 120
#define BT (BATCH*SEQ)          // 384
#define ROWS (BT*N_NODES)       // 65280
#define FF 2048

typedef short short8 __attribute__((ext_vector_type(8)));
typedef float f32x4 __attribute__((ext_vector_type(4)));

// ---------------- workspace layout (floats) ----------------
static constexpr size_t OFF_A    = 0;          // 86,704
static constexpr size_t OFF_G    = 86704;
static constexpr size_t OFF_A2   = 173408;
static constexpr size_t OFF_L    = 260112;     // L_bf bf16 3*31808 ush = 47,712 fl
static constexpr size_t OFF_RS1  = 307824;
static constexpr size_t OFF_RS2  = 308336;
static constexpr size_t OFF_RS3  = 308848;
static constexpr size_t OFF_XT   = 309360;                   // 4,325,376 fl
static constexpr size_t OFF_XNM  = OFF_XT  + 4325376;        // 4,177,920 -> end 8,812,656
static constexpr size_t OFF_HK   = OFF_XNM + 4177920;        // 4,177,920
static constexpr size_t OFF_HV   = OFF_HK  + 4177920;        // 4,177,920 -> end 17,168,496
static constexpr size_t OFF_YNM  = OFF_HV  + 4177920;        // 3x8,355,840 -> end 42,236,016
static constexpr size_t OFF_BC   = OFF_YNM + 3*8355840;      // 73,728
static constexpr size_t OFF_W1T  = OFF_BC  + 73728;          // 131,072
static constexpr size_t OFF_W2R  = OFF_W1T + 131072;         // 131,072
static constexpr size_t OFF_OWT  = OFF_W2R + 131072;         // 8,192 -> end 42,580,080 (<47,350,016 proven)
// aliases inside ynm region (dead after combine):
static constexpr size_t OFF_HQ   = OFF_XT;                   // xT dead after lapply2
static constexpr size_t OFF_ONM  = OFF_YNM;                  // 4,177,920
static constexpr size_t OFF_LN1  = OFF_ONM + 4177920;        // 7,833,600
static constexpr size_t OFF_LN1B = OFF_LN1 + 7833600;        // 4,177,920 -> end 33,357,936 (inside ynm ✓)

static constexpr size_t YNM_BR_STRIDE = 16711680;  // ushorts per branch

__device__ __forceinline__ unsigned short f2bf(float f) {
    unsigned int u = __float_as_uint(f);
    unsigned int r = (u + 0x7fffu + ((u >> 16) & 1u)) >> 16;
    return (unsigned short)r;
}
__device__ __forceinline__ float bf2f(unsigned short h) {
    return __uint_as_float(((unsigned int)h) << 16);
}
__device__ __forceinline__ unsigned cvt_pk_bf16(float lo, float hi) {
    unsigned r;
    asm volatile("v_cvt_pk_bf16_f32 %0, %1, %2" : "=v"(r) : "v"(lo), "v"(hi));
    return r;
}
__device__ __forceinline__ void gld16(const void* g, void* l) {
    __builtin_amdgcn_global_load_lds(
        (const __attribute__((address_space(1))) void*)g,
        (__attribute__((address_space(3))) void*)l, 16, 0, 0);
}
__device__ __forceinline__ uint4 pack8(const unsigned short v[8]) {
    uint4 q;
    q.x = (unsigned)v[0] | ((unsigned)v[1] << 16);
    q.y = (unsigned)v[2] | ((unsigned)v[3] << 16);
    q.z = (unsigned)v[4] | ((unsigned)v[5] << 16);
    q.w = (unsigned)v[6] | ((unsigned)v[7] << 16);
    return q;
}

// ================= graph-learn stage 1 =================
__global__ __launch_bounds__(256)
void k_gl1(const float* __restrict__ adj, const float* __restrict__ beta,
           const float* __restrict__ w1, const float* __restrict__ w2,
           const float* __restrict__ cw, const float* __restrict__ cb,
           float* __restrict__ a_out, float* __restrict__ rs_out) {
    int i  = blockIdx.x;
    int br = blockIdx.y;
    __shared__ float w1r[DM], w2r[DM];
    __shared__ float red[256];
    int tid = threadIdx.x;
    const float* w1b = w1 + (size_t)br * N_NODES * DM;
    const float* w2b = w2 + (size_t)br * N_NODES * DM;
    if (tid < DM) {
        w1r[tid] = w1b[(size_t)i * DM + tid];
        w2r[tid] = w2b[(size_t)i * DM + tid];
    }
    __syncthreads();
    float aval = 0.f;
    if (tid < N_NODES) {
        int j = tid;
        const float4* w1j = (const float4*)(w1b + (size_t)j * DM);
        const float4* w2j = (const float4*)(w2b + (size_t)j * DM);
        float s1 = 0.f, s2 = 0.f;
#pragma unroll 6
        for (int cc = 0; cc < DM / 4; ++cc) {
            float4 u = w2j[cc];
            float4 v = w1j[cc];
            s1 += w1r[cc*4+0]*u.x + w1r[cc*4+1]*u.y + w1r[cc*4+2]*u.z + w1r[cc*4+3]*u.w;
            s2 += w2r[cc*4+0]*v.x + w2r[cc*4+1]*v.y + w2r[cc*4+2]*v.z + w2r[cc*4+3]*v.w;
        }
        float nv = s1 - s2 + (j == i ? beta[br * N_NODES + i] : 0.f);
        nv = fmaxf(nv, 0.f);
        float adjv = adj[(size_t)i * N_NODES + j];
        float z = cw[br*2+0] * nv + cw[br*2+1] * adjv + cb[br];
        float gate = 1.f / (1.f + __expf(-z));
        aval = gate * nv + (1.f - gate) * adjv;
        a_out[((size_t)br * N_NODES + i) * N_NODES + j] = aval;
    }
    red[tid] = aval;
    __syncthreads();
    for (int s = 128; s > 0; s >>= 1) {
        if (tid < s) red[tid] += red[tid + s];
        __syncthreads();
    }
    if (tid == 0) rs_out[br * N_NODES + i] = red[0];
}

// ================= graph-learn normalize passes (modes 2,3) =================
__global__ __launch_bounds__(256)
void k_glnorm(const float* __restrict__ in, const float* __restrict__ rs,
              float* __restrict__ out, float* __restrict__ rs_out, int mode) {
    int i  = blockIdx.x;
    int br = blockIdx.y;
    __shared__ float red[256];
    int tid = threadIdx.x;
    float di = rsqrtf(rs[br * N_NODES + i]);
    float contrib = 0.f;
    if (tid < N_NODES) {
        float dj = rsqrtf(rs[br * N_NODES + tid]);
        float v = di * in[((size_t)br * N_NODES + i) * N_NODES + tid] * dj;
        float o;
        if (mode == 2) { o = fmaxf(v - 0.5f / 170.f, 0.f); contrib = o; }
        else           { o = v; contrib = v; }
        out[((size_t)br * N_NODES + i) * N_NODES + tid] = o;
    }
    red[tid] = contrib;
    __syncthreads();
    for (int s = 128; s > 0; s >>= 1) {
        if (tid < s) red[tid] += red[tid + s];
        __syncthreads();
    }
    if (tid == 0) rs_out[br * N_NODES + i] = red[0];
}

// ================= L prep: L_bf[br][176][180] bf16, zero-padded =================
__global__ __launch_bounds__(192)
void k_prep_L(const float* __restrict__ g_buf, const float* __restrict__ rs3,
              unsigned short* __restrict__ Lbf) {
    int i  = blockIdx.x;   // 0..175
    int br = blockIdx.y;
    int j  = threadIdx.x;
    if (j >= 180) return;
    float v = 0.f;
    if (i < N_NODES && j < N_NODES) {
        float di = rsqrtf(rs3[br * N_NODES + i]);
        float dj = rsqrtf(rs3[br * N_NODES + j]);
        float gg = g_buf[((size_t)br * N_NODES + i) * N_NODES + j];
        v = (i == j ? 1.f : 0.f) - di * gg * dj;
    }
    Lbf[(size_t)br * 31808 + i * 180 + j] = f2bf(v);
}

// ================= x prep: xTF (frag-linear channel-major) + x_nm (node-major swizzled) =========
__global__ __launch_bounds__(256)
void k_prep_x(const float* __restrict__ x, unsigned short* __restrict__ xTF,
              unsigned short* __restrict__ xnm) {
    __shared__ unsigned short LX[170 * 121 + 8];
    int bt = blockIdx.x, tid = threadIdx.x;
    const float* xb = x + (size_t)bt * N_NODES * DM;
    for (int u = tid; u < 170 * 30; u += 256) {
        int nn = u / 30, cq = u - nn * 30;
        float4 v = *(const float4*)&xb[nn * 120 + cq * 4];
        LX[nn * 121 + cq * 4 + 0] = f2bf(v.x);
        LX[nn * 121 + cq * 4 + 1] = f2bf(v.y);
        LX[nn * 121 + cq * 4 + 2] = f2bf(v.z);
        LX[nn * 121 + cq * 4 + 3] = f2bf(v.w);
    }
    __syncthreads();
    for (int u = tid; u < 128 * 22; u += 256) {
        int c = u / 22, mb = u - c * 22;
        unsigned short vals[8];
#pragma unroll
        for (int i2 = 0; i2 < 8; ++i2) {
            int m = mb * 8 + i2;
            vals[i2] = (c < 120 && m < 170) ? LX[m * 121 + c] : (unsigned short)0;
        }
        *(uint4*)&xTF[(size_t)bt * 22528 + ((size_t)mb * 128 + c) * 8] = pack8(vals);
    }
    for (int u = tid; u < 170 * 16; u += 256) {
        int nn = u >> 4, b = u & 15;
        unsigned int row = bt * 170 + nn;
        unsigned short vals[8];
#pragma unroll
        for (int i2 = 0; i2 < 8; ++i2) {
            int c = b * 8 + i2;
            vals[i2] = (c < 120) ? LX[nn * 121 + c] : (unsigned short)0;
        }
        int bs = (b & 8) | ((b & 7) ^ (row & 7));
        *(uint4*)&xnm[(size_t)row * 128 + bs * 8] = pack8(vals);
    }
}

// ================= merged weight prep: W1T, W2R, OwT, Bc (all frag layouts) =================
__global__ __launch_bounds__(256)
void k_prep_weights(const float* __restrict__ ff_w1, const float* __restrict__ ff_w2,
                    const float* __restrict__ out_w, const float* __restrict__ cheb_w,
                    unsigned short* __restrict__ W1T, unsigned short* __restrict__ W2R,
                    unsigned short* __restrict__ OwT, unsigned short* __restrict__ Bc) {
    int idx = blockIdx.x * 256 + threadIdx.x;
    if (idx < 262144) {                     // W1T[o][kpos] swizzled
        int o = idx >> 7, k = idx & 127;
        int b = k >> 3, ki = k & 7;
        int pos = (((b ^ (o & 7)) << 3) | ki);
        float v = (k < DM) ? ff_w1[(size_t)k * FF + o] : 0.f;
        W1T[(size_t)o * 128 + pos] = f2bf(v);
    } else if (idx < 524288) {              // W2R[c][o][jpos] swizzled
        int i = idx - 262144;
        int c = i >> 13;
        int o = (i >> 6) & 127;
        int j = i & 63;
        int b = j >> 3, ji = j & 7;
        int pos = (((b ^ (o & 7)) << 3) | ji);
        float v = (o < DM) ? ff_w2[(size_t)(c * 64 + j) * DM + o] : 0.f;
        W2R[((size_t)c << 13) + (o << 6) + pos] = f2bf(v);
    } else if (idx < 540672) {              // OwT frag-linear
        int i = idx - 524288;
        int o = i >> 7, c = i & 127;
        float v = (o < 120 && c < 120) ? out_w[(size_t)c * 120 + o] : 0.f;
        OwT[(((size_t)(c >> 3) * 128 + o) << 3) + (c & 7)] = f2bf(v);
    } else {                                // Bc frag-linear
        int i = idx - 540672;               // 3*128*384
        int br  = i / 49152;
        int rem = i - br * 49152;
        int o   = rem / 384;
        int c   = rem - o * 384;
        float v = 0.f;
        if (o < 120) {
            int part = c >> 7, cc = c & 127;
            if (cc < 120) {
                const float* Wb = cheb_w + (size_t)br * 3 * 14400;
                if (part == 0)      v = Wb[cc * 120 + o] - Wb[2 * 14400 + cc * 120 + o];
                else if (part == 1) v = Wb[14400 + cc * 120 + o];
                else                v = 2.f * Wb[2 * 14400 + cc * 120 + o];
            }
        }
        Bc[(size_t)br * 49152 + (((size_t)(c >> 3) * 128 + o) << 3) + (c & 7)] = f2bf(v);
    }
}

// ================= fused double-hop L-apply: y1 = L-hop(x) (LDS), y2 = L-hop(y1) =================
#define MP 184
__global__ __launch_bounds__(256)
void k_lapply2(const unsigned short* __restrict__ xTg,
               const unsigned short* __restrict__ Lg_base,
               unsigned short* __restrict__ ynm_base) {
    __shared__ __attribute__((aligned(16))) unsigned short Llds[31744];   // 63488 B
    __shared__ __attribute__((aligned(16))) unsigned short Y1[128 * MP];  // 47104 B
    const int tid = threadIdx.x, w = tid >> 6, lane = tid & 63;
    const int g = lane >> 4, l15 = lane & 15;
    const int bt = blockIdx.x, br = blockIdx.y;
    const unsigned short* Asrc = xTg + (size_t)bt * 22528;
    const unsigned short* Lg   = Lg_base + (size_t)br * 31808;
    unsigned short* ynm = ynm_base + (size_t)br * YNM_BR_STRIDE;
    const char* Lgb = (const char*)Lg;
    char* Lldsb = (char*)Llds;
#pragma unroll
    for (int it = 0; it < 16; ++it) {
        int q = it * 4 + w;
        if (q * 1024 < 63360)
            gld16(Lgb + q * 1024 + lane * 16, Lldsb + q * 1024);
    }
    short8 af[2][6];
#pragma unroll
    for (int ct2 = 0; ct2 < 2; ++ct2) {
        int c = (w * 2 + ct2) * 16 + l15;
#pragma unroll
        for (int kb = 0; kb < 6; ++kb) {
            if (kb < 5) af[ct2][kb] = *(const short8*)&Asrc[(((size_t)(kb * 4 + g)) * 128 + c) * 8];
            else {
                short8 z = {};
                af[ct2][kb] = (g < 2) ? *(const short8*)&Asrc[(((size_t)(20 + g)) * 128 + c) * 8] : z;
            }
        }
    }
    __syncthreads();
    f32x4 acc[2][11];

    for (int hop = 0; hop < 2; ++hop) {
#pragma unroll
        for (int a = 0; a < 2; ++a)
#pragma unroll
            for (int b = 0; b < 11; ++b) acc[a][b] = (f32x4){0.f, 0.f, 0.f, 0.f};
#pragma unroll
        for (int kb = 0; kb < 6; ++kb) {
#pragma unroll
            for (int nt = 0; nt < 11; ++nt) {
                short8 bf;
                int rb = (nt * 16 + l15) * 180;
                if (kb < 5) bf = *(const short8*)&Llds[rb + kb * 32 + g * 8];
                else {
                    short8 z = {};
                    bf = (g < 2) ? *(const short8*)&Llds[rb + 160 + g * 8] : z;
                }
                acc[0][nt] = __builtin_amdgcn_mfma_f32_16x16x32_bf16(af[0][kb], bf, acc[0][nt], 0, 0, 0);
                acc[1][nt] = __builtin_amdgcn_mfma_f32_16x16x32_bf16(af[1][kb], bf, acc[1][nt], 0, 0, 0);
            }
        }
        const int coloff = hop * 128;
#pragma unroll
        for (int nt = 0; nt < 11; ++nt) {
            int nn = nt * 16 + l15;
#pragma unroll
            for (int ct2 = 0; ct2 < 2; ++ct2) {
                int base_c = (w * 2 + ct2) * 16 + g * 4;
                if (hop == 0) {
#pragma unroll
                    for (int r = 0; r < 4; ++r)
                        Y1[(base_c + r) * MP + nn] = f2bf(acc[ct2][nt][r]);
                }
                if (nn < 170) {
                    unsigned int row = bt * 170 + nn;
                    unsigned short u[4];
#pragma unroll
                    for (int r = 0; r < 4; ++r)
                        u[r] = (base_c + r < 120) ? f2bf(acc[ct2][nt][r]) : (unsigned short)0;
                    int bc  = coloff + base_c;
                    int blk = bc >> 3;
                    int bsw = (blk & 24) | ((blk & 7) ^ (row & 7));
                    uint2 pk;
                    pk.x = (unsigned)u[0] | ((unsigned)u[1] << 16);
                    pk.y = (unsigned)u[2] | ((unsigned)u[3] << 16);
                    *(uint2*)&ynm[(size_t)row * 256 + bsw * 8 + (bc & 7)] = pk;
                }
            }
        }
        if (hop == 0) {
            __syncthreads();
#pragma unroll
            for (int ct2 = 0; ct2 < 2; ++ct2) {
                int c = (w * 2 + ct2) * 16 + l15;
#pragma unroll
                for (int kb = 0; kb < 6; ++kb) {
                    if (kb < 5) af[ct2][kb] = *(const short8*)&Y1[c * MP + kb * 32 + g * 8];
                    else {
                        short8 z = {};
                        af[ct2][kb] = (g < 2) ? *(const short8*)&Y1[c * MP + 160 + g * 8] : z;
                    }
                }
            }
        }
    }
}

// ================= MFMA Cheb combine (frag-linear B) =================
__global__ __launch_bounds__(256)
void k_combine_mfma(const unsigned short* __restrict__ xnm,
                    const unsigned short* __restrict__ ynm_base,
                    const unsigned short* __restrict__ Bc_base,
                    const float* __restrict__ bias_base,
                    unsigned short* __restrict__ h0,
                    unsigned short* __restrict__ h1,
                    unsigned short* __restrict__ h2) {
    __shared__ __attribute__((aligned(16))) unsigned short AsX[64 * 128];
    __shared__ __attribute__((aligned(16))) unsigned short AsY[64 * 256];
    const int tid = threadIdx.x, w = tid >> 6, lane = tid & 63;
    const int g = lane >> 4, l15 = lane & 15;
    const int r0 = blockIdx.x * 64;
    const int br = blockIdx.y;
    const unsigned short* ynm = ynm_base + (size_t)br * YNM_BR_STRIDE;
    const unsigned short* Bc  = Bc_base + (size_t)br * 49152;
    const float* bias = bias_base + br * DM;
    unsigned short* Hout = (br == 0) ? h0 : (br == 1) ? h1 : h2;
#pragma unroll
    for (int it = 0; it < 4; ++it) {
        int q = w * 4 + it;
        gld16(xnm + (size_t)r0 * 128 + q * 512 + lane * 8, &AsX[q * 512]);
    }
#pragma unroll
    for (int it = 0; it < 8; ++it) {
        int q = w * 8 + it;
        gld16(ynm + (size_t)r0 * 256 + q * 512 + lane * 8, &AsY[q * 512]);
    }
    __syncthreads();
    const int lr = w * 16 + l15;
    short8 af[12];
#pragma unroll
    for (int kb = 0; kb < 4; ++kb) {
        int b = kb * 4 + g;
        int bs = (b & 8) | ((b & 7) ^ (lr & 7));
        af[kb] = *(const short8*)&AsX[lr * 128 + bs * 8];
    }
#pragma unroll
    for (int kb = 4; kb < 12; ++kb) {
        int b = (kb - 4) * 4 + g;
        int bs = (b & 24) | ((b & 7) ^ (lr & 7));
        af[kb] = *(const short8*)&AsY[lr * 256 + bs * 8];
    }
    f32x4 acc[8];
#pragma unroll
    for (int c = 0; c < 8; ++c) acc[c] = (f32x4){0.f, 0.f, 0.f, 0.f};
    short8 bfA[8], bfB[8];
#pragma unroll
    for (int c = 0; c < 8; ++c)
        bfA[c] = *(const short8*)&Bc[(((size_t)g) * 128 + c * 16 + l15) * 8];
#pragma unroll
    for (int kb = 0; kb < 12; ++kb) {
        if (kb + 1 < 12) {
#pragma unroll
            for (int c = 0; c < 8; ++c) {
                short8 v = *(const short8*)&Bc[(((size_t)((kb + 1) * 4 + g)) * 128 + c * 16 + l15) * 8];
                if (kb & 1) bfA[c] = v; else bfB[c] = v;
            }
        }
#pragma unroll
        for (int c = 0; c < 8; ++c)
            acc[c] = __builtin_amdgcn_mfma_f32_16x16x32_bf16(af[kb], (kb & 1) ? bfB[c] : bfA[c], acc[c], 0, 0, 0);
    }
#pragma unroll
    for (int c = 0; c < 8; ++c) {
        int o = c * 16 + l15;
        float bv = (o < 120) ? bias[o] : 0.f;
#pragma unroll
        for (int r = 0; r < 4; ++r) {
            int row = r0 + w * 16 + g * 4 + r;
            float v = (o < 120) ? fmaxf(acc[c][r] + bv, 0.f) : 0.f;
            Hout[(size_t)row * 128 + o] = f2bf(v);
        }
    }
}

// ================= attention core: softmax(QK^T/s)V per (b, 2 nodes) =================
#define QP 136
__global__ __launch_bounds__(192)
void k_attn_qkv(const unsigned short* __restrict__ hq, const unsigned short* __restrict__ hk,
                const unsigned short* __restrict__ hv, unsigned short* __restrict__ onm) {
    __shared__ unsigned short qs[2][SEQ][QP], ks[2][SEQ][QP], vs[2][SEQ][QP], os[2][SEQ][QP];
    const int tid = threadIdx.x;
    const int np = blockIdx.x, b = blockIdx.y;
    for (int u = tid; u < 2 * SEQ * 16; u += 192) {
        int node = u / (SEQ * 16);
        int rem = u - node * SEQ * 16;
        int t = rem >> 4, seg = rem & 15;
        int n = np * 2 + node;
        size_t row = ((size_t)(b * SEQ + t) * N_NODES + n);
        *(uint4*)&qs[node][t][seg * 8] = *(const uint4*)&hq[row * 128 + seg * 8];
        *(uint4*)&ks[node][t][seg * 8] = *(const uint4*)&hk[row * 128 + seg * 8];
        *(uint4*)&vs[node][t][seg * 8] = *(const uint4*)&hv[row * 128 + seg * 8];
    }
    __syncthreads();
    {
        const int node = tid / 96, sub = tid % 96;
        const int h = sub & 7, tq = sub >> 3;
        float qr[15];
#pragma unroll
        for (int d = 0; d < 15; ++d) qr[d] = bf2f(qs[node][tq][h * 15 + d]);
        float sc[SEQ];
        float mx = -1e30f;
#pragma unroll
        for (int tk = 0; tk < SEQ; ++tk) {
            float s = 0.f;
#pragma unroll
            for (int d = 0; d < 15; ++d) s += qr[d] * bf2f(ks[node][tk][h * 15 + d]);
            s *= 0.25819888974716113f;
            sc[tk] = s;
            mx = fmaxf(mx, s);
        }
        float sum = 0.f;
#pragma unroll
        for (int tk = 0; tk < SEQ; ++tk) { sc[tk] = __expf(sc[tk] - mx); sum += sc[tk]; }
        float inv = 1.f / sum;
#pragma unroll
        for (int d = 0; d < 15; ++d) {
            float o = 0.f;
#pragma unroll
            for (int tk = 0; tk < SEQ; ++tk) o += sc[tk] * bf2f(vs[node][tk][h * 15 + d]);
            os[node][tq][h * 15 + d] = f2bf(o * inv);
        }
    }
    if (tid < 2 * SEQ) {
        int node = tid / SEQ, t = tid % SEQ;
#pragma unroll
        for (int j = 0; j < 8; ++j) os[node][t][120 + j] = 0;
    }
    __syncthreads();
    for (int u = tid; u < 2 * SEQ * 16; u += 192) {
        int node = u / (SEQ * 16);
        int rem = u - node * SEQ * 16;
        int t = rem >> 4, seg = rem & 15;
        int n = np * 2 + node;
        unsigned int row = (b * SEQ + t) * N_NODES + n;
        int bs = (seg & 8) | ((seg & 7) ^ (row & 7));
        *(uint4*)&onm[(size_t)row * 128 + bs * 8] = *(const uint4*)&os[node][t][seg * 8];
    }
}

// ================= MFMA out-proj + residual + LN1 (frag-linear B) =================
__global__ __launch_bounds__(256)
void k_outproj(const unsigned short* __restrict__ onm, const unsigned short* __restrict__ OwT,
               const float* __restrict__ outb, const float* __restrict__ x,
               const float* __restrict__ g1, const float* __restrict__ be1,
               float* __restrict__ ln1, unsigned short* __restrict__ ln1bf) {
    __shared__ __attribute__((aligned(16))) unsigned short As[64 * 128];
    const int tid = threadIdx.x, w = tid >> 6, lane = tid & 63;
    const int g = lane >> 4, l15 = lane & 15;
    const int r0 = blockIdx.x * 64;
#pragma unroll
    for (int it = 0; it < 4; ++it) {
        int q = w * 4 + it;
        gld16(onm + (size_t)r0 * 128 + q * 512 + lane * 8, &As[q * 512]);
    }
    __syncthreads();
    const int lr = w * 16 + l15;
    short8 af[4];
#pragma unroll
    for (int kb = 0; kb < 4; ++kb) {
        int b = kb * 4 + g;
        int bs = (b & 8) | ((b & 7) ^ (lr & 7));
        af[kb] = *(const short8*)&As[lr * 128 + bs * 8];
    }
    f32x4 acc[8];
#pragma unroll
    for (int c = 0; c < 8; ++c) acc[c] = (f32x4){0.f, 0.f, 0.f, 0.f};
#pragma unroll
    for (int kb = 0; kb < 4; ++kb) {
#pragma unroll
        for (int c = 0; c < 8; ++c) {
            short8 bf = *(const short8*)&OwT[(((size_t)(kb * 4 + g)) * 128 + c * 16 + l15) * 8];
            acc[c] = __builtin_amdgcn_mfma_f32_16x16x32_bf16(af[kb], bf, acc[c], 0, 0, 0);
        }
    }
#pragma unroll
    for (int r = 0; r < 4; ++r) {
        int row = w * 16 + g * 4 + r;
        size_t grow = (size_t)(r0 + row);
        float vals[8];
        float s = 0.f, q = 0.f;
#pragma unroll
        for (int c = 0; c < 8; ++c) {
            int col = c * 16 + l15;
            float v = 0.f;
            if (col < DM) v = acc[c][r] + outb[col] + x[grow * DM + col];
            vals[c] = v;
            s += v; q += v * v;
        }
#pragma unroll
        for (int m = 1; m < 16; m <<= 1) {
            s += __shfl_xor(s, m);
            q += __shfl_xor(q, m);
        }
        float mean = s * (1.f / DM);
        float var  = q * (1.f / DM) - mean * mean;
        float rstd = rsqrtf(var + 1e-5f);
#pragma unroll
        for (int c = 0; c < 8; ++c) {
            int col = c * 16 + l15;
            float o = (vals[c] - mean) * rstd * ((col < DM) ? g1[col] : 0.f) + ((col < DM) ? be1[col] : 0.f);
            if (col < DM) ln1[grow * DM + col] = o;
            ln1bf[grow * 128 + col] = (col < DM) ? f2bf(o) : (unsigned short)0;
        }
    }
}

// ================= MFMA FFN v3: wave-private H, ONE barrier per chunk =================
// Wave w owns X rows w*16..+15. Phase A: H[own16][all 64 hid] via mfma(w1frag, xfrag)
// (lane holds 4 consecutive hidden -> cvt_pk + uint2 store to wave-private HS slice).
// Phase B: accO += H(own rows) @ W2chunk, reads own HS slice (no cross-wave -> no barrier).
#define LDS_W1A 0
#define LDS_W2A 8192
#define LDS_W1B 16384
#define LDS_W2B 24576
#define LDS_HS  32768      // 64 x 72 ushorts (wave-private 16-row slices)
__global__ __launch_bounds__(256, 2)
void k_ffn_mfma(const unsigned short* __restrict__ Xbf,
                const float* __restrict__ ln1,
                const unsigned short* __restrict__ W1T,
                const float* __restrict__ b1,
                const unsigned short* __restrict__ W2R,
                const float* __restrict__ b2,
                const float* __restrict__ g2, const float* __restrict__ be2,
                float* __restrict__ Out) {
    __shared__ unsigned short lds[37376];
    const int tid  = threadIdx.x;
    const int w    = tid >> 6;
    const int lane = tid & 63;
    const int g    = lane >> 4;
    const int l15  = lane & 15;
    const int r0   = blockIdx.x * 64;
    // prologue: X -> W1B region (temp), chunk0 -> W1A/W2A
    {
        const unsigned short* xsrc = Xbf + (size_t)r0 * 128;
#pragma unroll
        for (int it = 0; it < 4; ++it) {
            int seg = w * 4 + it;
            gld16(xsrc + seg * 512 + lane * 8, &lds[LDS_W1B + seg * 512]);
            gld16(W1T + seg * 512 + lane * 8, &lds[LDS_W1A + seg * 512]);
            gld16(W2R + seg * 512 + lane * 8, &lds[LDS_W2A + seg * 512]);
        }
    }
    __syncthreads();
    // own-row X fragments (B-operand): lane provides X^T[k][xrow w*16+l15]
    short8 xfrag[4];
#pragma unroll
    for (int kk = 0; kk < 4; ++kk)
        xfrag[kk] = *(const short8*)&lds[LDS_W1B + (w * 16 + l15) * 128 + kk * 32 + g * 8];
    __syncthreads();   // all xfrags read before chunk-1 prefetch may overwrite W1B

    f32x4 accO[8] = {};
    unsigned short* hs = &lds[LDS_HS + (w * 16 + l15) * 72];        // own-row H slice
    const unsigned short* hsr = &lds[LDS_HS + (w * 16 + l15) * 72]; // read view (same)

    for (int t = 0; t < 32; ++t) {
        if (t) __syncthreads();    // chunk t staged (vmcnt drain) + prev readers done
        const int p = t & 1;
        if (t + 1 < 32) {
            const unsigned short* w1src = W1T + (size_t)(t + 1) * 8192;
            const unsigned short* w2src = W2R + (size_t)(t + 1) * 8192;
            unsigned short* w1dst = &lds[p ? LDS_W1A : LDS_W1B];
            unsigned short* w2dst = &lds[p ? LDS_W2A : LDS_W2B];
#pragma unroll
            for (int it = 0; it < 4; ++it) {
                int seg = w * 4 + it;
                gld16(w1src + seg * 512 + lane * 8, w1dst + seg * 512);
                gld16(w2src + seg * 512 + lane * 8, w2dst + seg * 512);
            }
        }
        const unsigned short* w1p = &lds[p ? LDS_W1B : LDS_W1A];
        const unsigned short* w2p = &lds[p ? LDS_W2B : LDS_W2A];
        // ---- phase A: accA[r] = H[xrow w*16+l15][hidden ct*16+g*4+r] ----
#pragma unroll
        for (int ct = 0; ct < 4; ++ct) {
            f32x4 accA = {};
#pragma unroll
            for (int kk = 0; kk < 4; ++kk) {
                short8 w1f = *(const short8*)&w1p[(ct * 16 + l15) * 128 + (((kk * 4 + g) ^ (l15 & 7)) << 3)];
                accA = __builtin_amdgcn_mfma_f32_16x16x32_bf16(w1f, xfrag[kk], accA, 0, 0, 0);
            }
            float4 b4 = *(const float4*)&b1[t * 64 + ct * 16 + g * 4];
            float h0 = fmaxf(accA[0] + b4.x, 0.f);
            float h1 = fmaxf(accA[1] + b4.y, 0.f);
            float h2 = fmaxf(accA[2] + b4.z, 0.f);
            float h3 = fmaxf(accA[3] + b4.w, 0.f);
            uint2 pk;
            pk.x = cvt_pk_bf16(h0, h1);
            pk.y = cvt_pk_bf16(h2, h3);
            *(uint2*)&hs[ct * 16 + g * 4] = pk;
        }
        // ---- phase B: accO += H(own rows) @ W2chunk (wave-private; lgkmcnt auto) ----
#pragma unroll
        for (int kk = 0; kk < 2; ++kk) {
            short8 hfrag = *(const short8*)&hsr[kk * 32 + g * 8];
            int b = kk * 4 + g;
#pragma unroll
            for (int c = 0; c < 8; ++c) {
                int o = c * 16 + l15;
                short8 w2f = *(const short8*)&w2p[(o << 6) + ((b ^ (o & 7)) << 3)];
                accO[c] = __builtin_amdgcn_mfma_f32_16x16x32_bf16(hfrag, w2f, accO[c], 0, 0, 0);
            }
        }
    }
    // ---- epilogue: +b2, +residual, LN2, store ----
#pragma unroll
    for (int r = 0; r < 4; ++r) {
        int row = w * 16 + g * 4 + r;
        size_t grow = (size_t)(r0 + row);
        float vals[8];
        float s = 0.f, q = 0.f;
#pragma unroll
        for (int c = 0; c < 8; ++c) {
            int col = c * 16 + l15;
            float v = 0.f;
            if (col < DM) v = accO[c][r] + b2[col] + ln1[grow * DM + col];
            vals[c] = v;
            s += v; q += v * v;
        }
#pragma unroll
        for (int m = 1; m < 16; m <<= 1) {
            s += __shfl_xor(s, m);
            q += __shfl_xor(q, m);
        }
        float mean = s * (1.f / DM);
        float var  = q * (1.f / DM) - mean * mean;
        float rstd = rsqrtf(var + 1e-5f);
#pragma unroll
        for (int c = 0; c < 8; ++c) {
            int col = c * 16 + l15;
            if (col < DM)
                Out[grow * DM + col] = (vals[c] - mean) * rstd * g2[col] + be2[col];
        }
    }
}

// ================================ launch ================================
extern "C" void kernel_launch(void* const* d_in, const int* in_sizes, int n_in,
                              void* d_out, int out_size, void* d_ws, size_t ws_size,
                              hipStream_t stream) {
    const float* x      = (const float*)d_in[0];
    const float* adj    = (const float*)d_in[1];
    const float* gl_beta= (const float*)d_in[2];
    const float* gl_w1  = (const float*)d_in[3];
    const float* gl_w2  = (const float*)d_in[4];
    const float* gl_cw  = (const float*)d_in[5];
    const float* gl_cb  = (const float*)d_in[6];
    const float* cheb_w = (const float*)d_in[7];
    const float* cheb_b = (const float*)d_in[8];
    const float* out_w  = (const float*)d_in[9];
    const float* out_b  = (const float*)d_in[10];
    const float* ff_w1  = (const float*)d_in[11];
    const float* ff_b1  = (const float*)d_in[12];
    const float* ff_w2  = (const float*)d_in[13];
    const float* ff_b2  = (const float*)d_in[14];
    const float* ln1_g  = (const float*)d_in[15];
    const float* ln1_b  = (const float*)d_in[16];
    const float* ln2_g  = (const float*)d_in[17];
    const float* ln2_b  = (const float*)d_in[18];

    float* ws    = (float*)d_ws;
    float* a_buf = ws + OFF_A;
    float* g_buf = ws + OFF_G;
    float* a2buf = ws + OFF_A2;
    float* rs1   = ws + OFF_RS1;
    float* rs2   = ws + OFF_RS2;
    float* rs3   = ws + OFF_RS3;
    unsigned short* L_bf = (unsigned short*)(ws + OFF_L);
    unsigned short* xT   = (unsigned short*)(ws + OFF_XT);
    unsigned short* xnm  = (unsigned short*)(ws + OFF_XNM);
    unsigned short* ynm  = (unsigned short*)(ws + OFF_YNM);
    unsigned short* Bc   = (unsigned short*)(ws + OFF_BC);
    unsigned short* hq   = (unsigned short*)(ws + OFF_HQ);
    unsigned short* hk   = (unsigned short*)(ws + OFF_HK);
    unsigned short* hv   = (unsigned short*)(ws + OFF_HV);
    unsigned short* W1T  = (unsigned short*)(ws + OFF_W1T);
    unsigned short* W2R  = (unsigned short*)(ws + OFF_W2R);
    unsigned short* OwT  = (unsigned short*)(ws + OFF_OWT);
    unsigned short* onm  = (unsigned short*)(ws + OFF_ONM);
    float*          ln1  = ws + OFF_LN1;
    unsigned short* ln1bf= (unsigned short*)(ws + OFF_LN1B);

    // weight preps (dedicated regions; independent of everything else)
    k_prep_weights<<<2688, 256, 0, stream>>>(ff_w1, ff_w2, out_w, cheb_w, W1T, W2R, OwT, Bc);

    // graph learning
    k_gl1   <<<dim3(N_NODES, 3), 256, 0, stream>>>(adj, gl_beta, gl_w1, gl_w2, gl_cw, gl_cb, a_buf, rs1);
    k_glnorm<<<dim3(N_NODES, 3), 256, 0, stream>>>(a_buf, rs1, a2buf, rs2, 2);
    k_glnorm<<<dim3(N_NODES, 3), 256, 0, stream>>>(a2buf, rs2, g_buf, rs3, 3);
    k_prep_L<<<dim3(176, 3), 192, 0, stream>>>(g_buf, rs3, L_bf);

    // x prep
    k_prep_x<<<BT, 256, 0, stream>>>(x, xT, xnm);

    // fused double-hop Cheb L-apply (all branches)
    k_lapply2<<<dim3(BT, 3), 256, 0, stream>>>(xT, L_bf, ynm);

    // Cheb combine (all branches)
    k_combine_mfma<<<dim3(ROWS / 64, 3), 256, 0, stream>>>(xnm, ynm, Bc, cheb_b, hq, hk, hv);

    // attention core -> o_nm (bf16 swizzled)
    k_attn_qkv<<<dim3(N_NODES / 2, BATCH), 192, 0, stream>>>(hq, hk, hv, onm);

    // out-proj + residual + LN1 (MFMA)
    k_outproj<<<ROWS / 64, 256, 0, stream>>>(onm, OwT, out_b, x, ln1_g, ln1_b, ln1, ln1bf);

    // FFN + residual + LN2 -> output
    k_ffn_mfma<<<ROWS / 64, 256, 0, stream>>>(ln1bf, ln1, W1T, ff_b1, W2R, ff_b2, ln2_g, ln2_b, (float*)d_out);
}